// Round 19
// baseline (189.844 us; speedup 1.0000x reference)
//
#include <hip/hip_runtime.h>
#include <hip/hip_fp16.h>

// Guided filter, B=4 H=1024 W=1024 C=4 f32 NHWC, r from d_in[2] (expected <=40).
// R18->R19: single-buffered LDS planes -> 2 blocks/CU for KA and KB.
// R13 measured 5.6-5.8 TB/s logical delivery at 2 blocks/CU vs 5.2 at 1.
// Single-buffering is race-free with the existing 2 lgkm barriers per row:
// plane writes for row k+1 occur after barrier1 of scan k+1, which orders
// them after all consume reads of row k; wt ordered by barrier2 (validated
// empirically in R13). No math or traffic change.
// kchunk  : I,p -> 16-row chunk sums of {I,p,Ip,II} (f32).
// kfusedAB: I,p (+chunks) -> vert sliding sums in regs -> per-row block scan
//           -> horizontal box -> A,b out (fp16) + A,b chunk sums (f32).
// kfusedQ : A,b (+AB chunks) -> same -> q = meanA*I + meanb -> d_out (f32).
// N = cntH(h)*cntW(w) analytic.

#define HD 1024
#define WD 1024
#define ROW4 WD                      // float4 pixels per row
#define IMG4 ((size_t)HD * ROW4)
#define IMGF (IMG4 * 4)
#define BH 16                        // output rows per block == chunk height
#define NB (HD / BH)                 // 64 bands
#define CH 16
#define NCH (HD / CH)                // 64 chunks
#define TPB 256
#define PPT 4                        // pixels per thread (full width)
#define PFXN 1153                    // idx4(1024)+1
#define EPS 1e-8f

__device__ __forceinline__ int idx4(int p) { return p + (p >> 3); }

// lgkm-only barrier: prefetched global loads stay in flight across it.
__device__ __forceinline__ void barrier_lds() {
    asm volatile("s_waitcnt lgkmcnt(0)" ::: "memory");
    __builtin_amdgcn_s_barrier();
}

struct H4 { __half2 lo, hi; };

__device__ __forceinline__ H4 pack4(float4 v) {
    H4 h; h.lo = __floats2half2_rn(v.x, v.y); h.hi = __floats2half2_rn(v.z, v.w);
    return h;
}
__device__ __forceinline__ float4 unpack4(H4 h) {
    float2 l = __half22float2(h.lo), u = __half22float2(h.hi);
    return make_float4(l.x, l.y, u.x, u.y);
}
__device__ __forceinline__ float4 packAB(H4 a, H4 b) {
    union { H4 h[2]; float4 f; } u; u.h[0] = a; u.h[1] = b; return u.f;
}
__device__ __forceinline__ float4 f4add(float4 a, float4 b) {
    return make_float4(a.x + b.x, a.y + b.y, a.z + b.z, a.w + b.w);
}
__device__ __forceinline__ float4 f4sub(float4 a, float4 b) {
    return make_float4(a.x - b.x, a.y - b.y, a.z - b.z, a.w - b.w);
}
__device__ __forceinline__ float4 f4s(float4 a, float s) {
    return make_float4(a.x * s, a.y * s, a.z * s, a.w * s);
}
__device__ __forceinline__ float4 f4mul(float4 a, float4 b) {
    return make_float4(a.x * b.x, a.y * b.y, a.z * b.z, a.w * b.w);
}
__device__ __forceinline__ float4 shup4(float4 v, int d) {
    return make_float4(__shfl_up(v.x, d), __shfl_up(v.y, d), __shfl_up(v.z, d), __shfl_up(v.w, d));
}
// 64 bands: XCD q = bx&7 gets bands 8q..8q+7. Bijective.
__device__ __forceinline__ int band_of(int bx) {
    return (bx >> 3) + (bx & 7) * 8;
}

// ---------------- K0: 16-row chunk sums of {I,p,Ip,II} (f32) ----------------
__global__ __launch_bounds__(TPB, 2) void kchunk(
    const float4* __restrict__ I4, const float4* __restrict__ P4,
    float4* __restrict__ Sc)
{
    const int cb = blockIdx.x;
    const int t = threadIdx.x;
    const size_t imgb = (size_t)blockIdx.y * IMG4;
    const float4* Ib = I4 + imgb + PPT * t;
    const float4* Pb = P4 + imgb + PPT * t;
    const float4 z4 = make_float4(0.f, 0.f, 0.f, 0.f);

    float4 sI[PPT], sp[PPT], sIp[PPT], sII[PPT];
    #pragma unroll
    for (int i = 0; i < PPT; ++i) { sI[i] = z4; sp[i] = z4; sIp[i] = z4; sII[i] = z4; }

    const int j0 = cb * CH;
    for (int j = j0; j < j0 + CH; j += 4) {
        float4 a[4][PPT], c[4][PPT];
        #pragma unroll
        for (int k = 0; k < 4; ++k) {
            const float4* Ir = Ib + (size_t)(j + k) * ROW4;
            const float4* Pr = Pb + (size_t)(j + k) * ROW4;
            #pragma unroll
            for (int i = 0; i < PPT; ++i) { a[k][i] = Ir[i]; c[k][i] = Pr[i]; }
        }
        #pragma unroll
        for (int k = 0; k < 4; ++k)
            #pragma unroll
            for (int i = 0; i < PPT; ++i) {
                sI[i] = f4add(sI[i], a[k][i]);
                sp[i] = f4add(sp[i], c[k][i]);
                sIp[i] = f4add(sIp[i], f4mul(a[k][i], c[k][i]));
                sII[i] = f4add(sII[i], f4mul(a[k][i], a[k][i]));
            }
    }

    const size_t fstride = (size_t)NCH * ROW4;
    float4* S = Sc + (size_t)blockIdx.y * 4 * fstride + (size_t)cb * ROW4 + PPT * t;
    #pragma unroll
    for (int i = 0; i < PPT; ++i) {
        S[i] = sI[i];
        S[fstride + i] = sp[i];
        S[2 * fstride + i] = sIp[i];
        S[3 * fstride + i] = sII[i];
    }
}

// Block scan of 4 fields (PPT=4/thread) into swizzled planes pl[f][idx4(p)].
// Single-buffered is race-free: pl writes occur only after barrier1, which
// orders them after all prior-row consume reads; wt ordered by barrier2.
__device__ __forceinline__ void scan4d(
    float4 (*pl)[PFXN], float4 (*wt)[4],
    const float4* s0, const float4* s1, const float4* s2, const float4* s3,
    int t, int lane, int wv)
{
    const float4 z4 = make_float4(0.f, 0.f, 0.f, 0.f);
    float4 p0[PPT], p1[PPT], p2[PPT], p3[PPT];
    p0[0] = s0[0]; p1[0] = s1[0]; p2[0] = s2[0]; p3[0] = s3[0];
    #pragma unroll
    for (int i = 1; i < PPT; ++i) {
        p0[i] = f4add(p0[i-1], s0[i]); p1[i] = f4add(p1[i-1], s1[i]);
        p2[i] = f4add(p2[i-1], s2[i]); p3[i] = f4add(p3[i-1], s3[i]);
    }
    float4 i0 = p0[3], i1 = p1[3], i2 = p2[3], i3 = p3[3];
    #pragma unroll
    for (int d = 1; d < 64; d <<= 1) {
        float4 t0 = shup4(i0, d), t1 = shup4(i1, d), t2 = shup4(i2, d), t3 = shup4(i3, d);
        if (lane >= d) {
            i0 = f4add(i0, t0); i1 = f4add(i1, t1);
            i2 = f4add(i2, t2); i3 = f4add(i3, t3);
        }
    }
    float4 e0 = shup4(i0, 1), e1 = shup4(i1, 1), e2 = shup4(i2, 1), e3 = shup4(i3, 1);
    if (lane == 0) { e0 = z4; e1 = z4; e2 = z4; e3 = z4; }
    if (lane == 63) { wt[wv][0] = i0; wt[wv][1] = i1; wt[wv][2] = i2; wt[wv][3] = i3; }
    barrier_lds();
    for (int wq = 0; wq < wv; ++wq) {
        e0 = f4add(e0, wt[wq][0]); e1 = f4add(e1, wt[wq][1]);
        e2 = f4add(e2, wt[wq][2]); e3 = f4add(e3, wt[wq][3]);
    }
    if (t == 0) {
        pl[0][idx4(0)] = z4; pl[1][idx4(0)] = z4;
        pl[2][idx4(0)] = z4; pl[3][idx4(0)] = z4;
    }
    #pragma unroll
    for (int i = 0; i < PPT; ++i) {
        int p = PPT * t + 1 + i;
        pl[0][idx4(p)] = f4add(e0, p0[i]);
        pl[1][idx4(p)] = f4add(e1, p1[i]);
        pl[2][idx4(p)] = f4add(e2, p2[i]);
        pl[3][idx4(p)] = f4add(e3, p3[i]);
    }
    barrier_lds();
}

__device__ __forceinline__ void scan2d(
    float4 (*pl)[PFXN], float4 (*wt)[2],
    const float4* s0, const float4* s1, int t, int lane, int wv)
{
    const float4 z4 = make_float4(0.f, 0.f, 0.f, 0.f);
    float4 p0[PPT], p1[PPT];
    p0[0] = s0[0]; p1[0] = s1[0];
    #pragma unroll
    for (int i = 1; i < PPT; ++i) {
        p0[i] = f4add(p0[i-1], s0[i]); p1[i] = f4add(p1[i-1], s1[i]);
    }
    float4 i0 = p0[3], i1 = p1[3];
    #pragma unroll
    for (int d = 1; d < 64; d <<= 1) {
        float4 t0 = shup4(i0, d), t1 = shup4(i1, d);
        if (lane >= d) { i0 = f4add(i0, t0); i1 = f4add(i1, t1); }
    }
    float4 e0 = shup4(i0, 1), e1 = shup4(i1, 1);
    if (lane == 0) { e0 = z4; e1 = z4; }
    if (lane == 63) { wt[wv][0] = i0; wt[wv][1] = i1; }
    barrier_lds();
    for (int wq = 0; wq < wv; ++wq) {
        e0 = f4add(e0, wt[wq][0]); e1 = f4add(e1, wt[wq][1]);
    }
    if (t == 0) { pl[0][idx4(0)] = z4; pl[1][idx4(0)] = z4; }
    #pragma unroll
    for (int i = 0; i < PPT; ++i) {
        int p = PPT * t + 1 + i;
        pl[0][idx4(p)] = f4add(e0, p0[i]);
        pl[1][idx4(p)] = f4add(e1, p1[i]);
    }
    barrier_lds();
}

// ---------------- KA: I,p (+chunks) -> A,b (fp16) + A,b chunk sums ----------------
__global__ __launch_bounds__(TPB, 2) void kfusedAB(
    const float4* __restrict__ I4, const float4* __restrict__ P4,
    const float4* __restrict__ Sc,
    H4* __restrict__ Aout, H4* __restrict__ Bout,
    float4* __restrict__ ScAB,
    const int* __restrict__ rptr)
{
    __shared__ float4 pl[4][PFXN];      // single-buffered, 73.8 KB -> 2 blocks/CU
    __shared__ float4 wt[4][4];
    const int r = *rptr;
    const int t = threadIdx.x, lane = t & 63, wv = t >> 6;
    const int band = band_of(blockIdx.x);
    const int h0 = band * BH;
    const size_t imgb = (size_t)blockIdx.y * IMG4;
    const float4* Ib = I4 + imgb + PPT * t;
    const float4* Pb = P4 + imgb + PPT * t;
    const size_t fstride = (size_t)NCH * ROW4;
    const float4* Scimg = Sc + (size_t)blockIdx.y * 4 * fstride + PPT * t;
    H4* Ao = Aout + imgb;
    H4* Bo = Bout + imgb;
    const float4 z4 = make_float4(0.f, 0.f, 0.f, 0.f);

    float4 sI[PPT], sp[PPT], sIp[PPT], sII[PPT];
    float4 cA[PPT], cB[PPT];            // A,b chunk-sum accumulators
    #pragma unroll
    for (int i = 0; i < PPT; ++i) {
        sI[i] = z4; sp[i] = z4; sIp[i] = z4; sII[i] = z4;
        cA[i] = z4; cB[i] = z4;
    }

    auto rawRows = [&](int a, int b) {
        int j = a;
        for (; j + 3 <= b; j += 4) {
            float4 aa[4][PPT], cc[4][PPT];
            #pragma unroll
            for (int k = 0; k < 4; ++k) {
                const float4* Ir = Ib + (size_t)(j + k) * ROW4;
                const float4* Pr = Pb + (size_t)(j + k) * ROW4;
                #pragma unroll
                for (int i = 0; i < PPT; ++i) { aa[k][i] = Ir[i]; cc[k][i] = Pr[i]; }
            }
            #pragma unroll
            for (int k = 0; k < 4; ++k)
                #pragma unroll
                for (int i = 0; i < PPT; ++i) {
                    sI[i] = f4add(sI[i], aa[k][i]);
                    sp[i] = f4add(sp[i], cc[k][i]);
                    sIp[i] = f4add(sIp[i], f4mul(aa[k][i], cc[k][i]));
                    sII[i] = f4add(sII[i], f4mul(aa[k][i], aa[k][i]));
                }
        }
        for (; j <= b; ++j) {
            const float4* Ir = Ib + (size_t)j * ROW4;
            const float4* Pr = Pb + (size_t)j * ROW4;
            #pragma unroll
            for (int i = 0; i < PPT; ++i) {
                float4 a1 = Ir[i], c1 = Pr[i];
                sI[i] = f4add(sI[i], a1); sp[i] = f4add(sp[i], c1);
                sIp[i] = f4add(sIp[i], f4mul(a1, c1));
                sII[i] = f4add(sII[i], f4mul(a1, a1));
            }
        }
    };

    int lo = h0 - r; if (lo < 0) lo = 0;
    int hi = h0 + r; if (hi > HD - 1) hi = HD - 1;
    int cb0 = (lo + CH - 1) / CH;
    int cb1 = (hi + 1) / CH - 1;
    if (cb0 > cb1) {
        rawRows(lo, hi);
    } else {
        if (lo < cb0 * CH) rawRows(lo, cb0 * CH - 1);
        for (int cb = cb0; cb <= cb1; ++cb) {
            const float4* S = Scimg + (size_t)cb * ROW4;
            float4 v0[PPT], v1[PPT], v2[PPT], v3[PPT];
            #pragma unroll
            for (int i = 0; i < PPT; ++i) {
                v0[i] = S[i];
                v1[i] = S[fstride + i];
                v2[i] = S[2 * fstride + i];
                v3[i] = S[3 * fstride + i];
            }
            #pragma unroll
            for (int i = 0; i < PPT; ++i) {
                sI[i] = f4add(sI[i], v0[i]);
                sp[i] = f4add(sp[i], v1[i]);
                sIp[i] = f4add(sIp[i], v2[i]);
                sII[i] = f4add(sII[i], v3[i]);
            }
        }
        if (hi >= (cb1 + 1) * CH) rawRows((cb1 + 1) * CH, hi);
    }

    for (int h = h0; h < h0 + BH; ++h) {
        int ja = h + 1 + r, js = h - r;
        float wa  = (ja <= HD - 1) ? 1.f : 0.f;
        float wsb = (js >= 0) ? 1.f : 0.f;
        int jac = (ja <= HD - 1) ? ja : HD - 1;
        int jsc = (js >= 0) ? js : 0;
        const float4* Iar = Ib + (size_t)jac * ROW4;
        const float4* Par = Pb + (size_t)jac * ROW4;
        const float4* Isr = Ib + (size_t)jsc * ROW4;
        const float4* Psr = Pb + (size_t)jsc * ROW4;
        float4 La[PPT], Ca[PPT], Ls[PPT], Cs[PPT];
        #pragma unroll
        for (int i = 0; i < PPT; ++i) {
            La[i] = Iar[i]; Ca[i] = Par[i];
            Ls[i] = Isr[i]; Cs[i] = Psr[i];
        }

        int hl = h - r; if (hl < 0) hl = 0;
        int hh = h + r; if (hh > HD - 1) hh = HD - 1;
        const float cntH = (float)(hh - hl + 1);

        scan4d(pl, wt, sI, sp, sIp, sII, t, lane, wv);

        H4 av[PPT], bv[PPT];
        #pragma unroll
        for (int i = 0; i < PPT; ++i) {
            int wp = PPT * t + i;
            int wl = wp - r; if (wl < 0) wl = 0;
            int wh2 = wp + r; if (wh2 > WD - 1) wh2 = WD - 1;
            float invN = 1.f / ((float)(wh2 - wl + 1) * cntH);
            int iA = idx4(wh2 + 1), iB = idx4(wl);
            float4 mI  = f4s(f4sub(pl[0][iA], pl[0][iB]), invN);
            float4 mp  = f4s(f4sub(pl[1][iA], pl[1][iB]), invN);
            float4 mIp = f4s(f4sub(pl[2][iA], pl[2][iB]), invN);
            float4 mII = f4s(f4sub(pl[3][iA], pl[3][iB]), invN);
            float4 cov = f4sub(mIp, f4mul(mI, mp));
            float4 var = f4sub(mII, f4mul(mI, mI));
            float4 Av = make_float4(cov.x / (var.x + EPS), cov.y / (var.y + EPS),
                                    cov.z / (var.z + EPS), cov.w / (var.w + EPS));
            float4 Bv = f4sub(mp, f4mul(Av, mI));
            cA[i] = f4add(cA[i], Av);
            cB[i] = f4add(cB[i], Bv);
            av[i] = pack4(Av); bv[i] = pack4(Bv);
        }
        {
            float4* Arow = (float4*)(Ao + (size_t)h * ROW4 + PPT * t);
            float4* Brow = (float4*)(Bo + (size_t)h * ROW4 + PPT * t);
            Arow[0] = packAB(av[0], av[1]); Arow[1] = packAB(av[2], av[3]);
            Brow[0] = packAB(bv[0], bv[1]); Brow[1] = packAB(bv[2], bv[3]);
        }

        #pragma unroll
        for (int i = 0; i < PPT; ++i) {
            float4 A1 = f4s(La[i], wa),  C1 = f4s(Ca[i], wa);
            float4 A2 = f4s(Ls[i], wsb), C2 = f4s(Cs[i], wsb);
            sI[i] = f4add(f4sub(sI[i], A2), A1);
            sp[i] = f4add(f4sub(sp[i], C2), C1);
            sIp[i] = f4add(sIp[i], f4sub(f4mul(A1, C1), f4mul(A2, C2)));
            sII[i] = f4add(sII[i], f4sub(f4mul(A1, A1), f4mul(A2, A2)));
        }
    }

    // store A,b chunk sums for this band (band == chunk since BH == CH)
    {
        const size_t f2 = (size_t)NCH * ROW4;
        float4* S2 = ScAB + (size_t)blockIdx.y * 2 * f2 + (size_t)band * ROW4 + PPT * t;
        #pragma unroll
        for (int i = 0; i < PPT; ++i) {
            S2[i] = cA[i];
            S2[f2 + i] = cB[i];
        }
    }
}

// ---------------- KB: A,b (+AB chunks) -> q = meanA*I + meanb ----------------
__global__ __launch_bounds__(TPB, 2) void kfusedQ(
    const H4* __restrict__ Ain, const H4* __restrict__ Bin,
    const float4* __restrict__ ScAB,
    const float4* __restrict__ I4, float4* __restrict__ Qout,
    const int* __restrict__ rptr)
{
    __shared__ float4 pl[2][PFXN];      // single-buffered, 36.9 KB
    __shared__ float4 wt[4][2];
    const int r = *rptr;
    const int t = threadIdx.x, lane = t & 63, wv = t >> 6;
    const int h0 = band_of(blockIdx.x) * BH;
    const size_t imgb = (size_t)blockIdx.y * IMG4;
    const H4* Abp = Ain + imgb + PPT * t;
    const H4* Bbp = Bin + imgb + PPT * t;
    const size_t f2 = (size_t)NCH * ROW4;
    const float4* S2img = ScAB + (size_t)blockIdx.y * 2 * f2 + PPT * t;
    const float4* Ib = I4 + imgb + PPT * t;
    float4* Qo = Qout + imgb;
    const float4 z4 = make_float4(0.f, 0.f, 0.f, 0.f);

    float4 sA[PPT], sB[PPT];
    #pragma unroll
    for (int i = 0; i < PPT; ++i) { sA[i] = z4; sB[i] = z4; }

    auto rawRows = [&](int a, int b) {
        int j = a;
        for (; j + 3 <= b; j += 4) {
            H4 aa[4][PPT], bb[4][PPT];
            #pragma unroll
            for (int k = 0; k < 4; ++k) {
                const H4* Ar = Abp + (size_t)(j + k) * ROW4;
                const H4* Br = Bbp + (size_t)(j + k) * ROW4;
                #pragma unroll
                for (int i = 0; i < PPT; ++i) { aa[k][i] = Ar[i]; bb[k][i] = Br[i]; }
            }
            #pragma unroll
            for (int k = 0; k < 4; ++k)
                #pragma unroll
                for (int i = 0; i < PPT; ++i) {
                    sA[i] = f4add(sA[i], unpack4(aa[k][i]));
                    sB[i] = f4add(sB[i], unpack4(bb[k][i]));
                }
        }
        for (; j <= b; ++j) {
            const H4* Ar = Abp + (size_t)j * ROW4;
            const H4* Br = Bbp + (size_t)j * ROW4;
            #pragma unroll
            for (int i = 0; i < PPT; ++i) {
                sA[i] = f4add(sA[i], unpack4(Ar[i]));
                sB[i] = f4add(sB[i], unpack4(Br[i]));
            }
        }
    };

    int lo = h0 - r; if (lo < 0) lo = 0;
    int hi = h0 + r; if (hi > HD - 1) hi = HD - 1;
    int cb0 = (lo + CH - 1) / CH;
    int cb1 = (hi + 1) / CH - 1;
    if (cb0 > cb1) {
        rawRows(lo, hi);
    } else {
        if (lo < cb0 * CH) rawRows(lo, cb0 * CH - 1);
        for (int cb = cb0; cb <= cb1; ++cb) {
            const float4* S = S2img + (size_t)cb * ROW4;
            float4 v0[PPT], v1[PPT];
            #pragma unroll
            for (int i = 0; i < PPT; ++i) {
                v0[i] = S[i];
                v1[i] = S[f2 + i];
            }
            #pragma unroll
            for (int i = 0; i < PPT; ++i) {
                sA[i] = f4add(sA[i], v0[i]);
                sB[i] = f4add(sB[i], v1[i]);
            }
        }
        if (hi >= (cb1 + 1) * CH) rawRows((cb1 + 1) * CH, hi);
    }

    for (int h = h0; h < h0 + BH; ++h) {
        int ja = h + 1 + r, js = h - r;
        float wa  = (ja <= HD - 1) ? 1.f : 0.f;
        float wsb = (js >= 0) ? 1.f : 0.f;
        int jac = (ja <= HD - 1) ? ja : HD - 1;
        int jsc = (js >= 0) ? js : 0;
        const H4* Aar = Abp + (size_t)jac * ROW4;
        const H4* Bar = Bbp + (size_t)jac * ROW4;
        const H4* Asr = Abp + (size_t)jsc * ROW4;
        const H4* Bsr = Bbp + (size_t)jsc * ROW4;
        const float4* Irow = Ib + (size_t)h * ROW4;
        H4 La[PPT], Lb[PPT], Sa[PPT], Sb[PPT];
        float4 iv[PPT];
        #pragma unroll
        for (int i = 0; i < PPT; ++i) {
            La[i] = Aar[i]; Lb[i] = Bar[i];
            Sa[i] = Asr[i]; Sb[i] = Bsr[i];
            iv[i] = Irow[i];
        }

        int hl = h - r; if (hl < 0) hl = 0;
        int hh = h + r; if (hh > HD - 1) hh = HD - 1;
        const float cntH = (float)(hh - hl + 1);

        scan2d(pl, wt, sA, sB, t, lane, wv);

        float4* Qrow = Qo + (size_t)h * ROW4 + PPT * t;
        #pragma unroll
        for (int i = 0; i < PPT; ++i) {
            int wp = PPT * t + i;
            int wl = wp - r; if (wl < 0) wl = 0;
            int wh2 = wp + r; if (wh2 > WD - 1) wh2 = WD - 1;
            float invN = 1.f / ((float)(wh2 - wl + 1) * cntH);
            int iA = idx4(wh2 + 1), iB = idx4(wl);
            float4 mA = f4s(f4sub(pl[0][iA], pl[0][iB]), invN);
            float4 mB = f4s(f4sub(pl[1][iA], pl[1][iB]), invN);
            Qrow[i] = make_float4(mA.x * iv[i].x + mB.x, mA.y * iv[i].y + mB.y,
                                  mA.z * iv[i].z + mB.z, mA.w * iv[i].w + mB.w);
        }

        #pragma unroll
        for (int i = 0; i < PPT; ++i) {
            float4 A1 = f4s(unpack4(La[i]), wa);
            float4 B1 = f4s(unpack4(Lb[i]), wa);
            float4 A2 = f4s(unpack4(Sa[i]), wsb);
            float4 B2 = f4s(unpack4(Sb[i]), wsb);
            sA[i] = f4add(f4sub(sA[i], A2), A1);
            sB[i] = f4add(f4sub(sB[i], B2), B1);
        }
    }
}

extern "C" void kernel_launch(void* const* d_in, const int* in_sizes, int n_in,
                              void* d_out, int out_size, void* d_ws, size_t ws_size,
                              hipStream_t stream)
{
    const float* I = (const float*)d_in[0];
    const float* P = (const float*)d_in[1];
    const int* rptr = (const int*)d_in[2];
    float* out = (float*)d_out;

    const int Bn = (int)(in_sizes[0] / IMGF);              // 4
    const size_t chunkBytes  = (size_t)4 * NCH * ROW4 * sizeof(float4);  // 4 MiB/img
    const size_t chunkABytes = (size_t)2 * NCH * ROW4 * sizeof(float4);  // 2 MiB/img
    const size_t perBatch = 2 * IMG4 * sizeof(H4) + chunkBytes + chunkABytes;

    int nbChunk = (int)(ws_size / perBatch);
    if (nbChunk < 1) nbChunk = 1;
    if (nbChunk > Bn) nbChunk = Bn;

    for (int b0 = 0; b0 < Bn; b0 += nbChunk) {
        const int nb = (b0 + nbChunk <= Bn) ? nbChunk : (Bn - b0);
        H4* Ah = (H4*)d_ws;
        H4* Bh = Ah + (size_t)nb * IMG4;
        float4* Sc = (float4*)(Bh + (size_t)nb * IMG4);
        float4* ScAB = Sc + (size_t)nb * 4 * NCH * ROW4;
        const float4* Ib = (const float4*)(I + (size_t)b0 * IMGF);
        const float4* Pb = (const float4*)(P + (size_t)b0 * IMGF);
        float4* ob = (float4*)(out + (size_t)b0 * IMGF);

        kchunk<<<dim3(NCH, nb), TPB, 0, stream>>>(Ib, Pb, Sc);
        kfusedAB<<<dim3(NB, nb), TPB, 0, stream>>>(Ib, Pb, Sc, Ah, Bh, ScAB, rptr);
        kfusedQ<<<dim3(NB, nb), TPB, 0, stream>>>(Ah, Bh, ScAB, Ib, ob, rptr);
    }
}

// Round 20
// 179.819 us; speedup vs baseline: 1.0557x; 1.0557x over previous
//
#include <hip/hip_runtime.h>
#include <hip/hip_fp16.h>

// Guided filter, B=4 H=1024 W=1024 C=4 f32 NHWC, r from d_in[2] (expected <=40).
// R20 = R18 verbatim (measured best: 180.4 us). R19's single-buffer attempt
// regressed (occupancy didn't double; lost row-pipeline overlap). R18:
// kchunk  : I,p -> 16-row chunk sums of {I,p,Ip,II} (f32).
// kfusedAB: I,p (+chunks) -> vert sliding sums in regs -> per-row block scan
//           (double-buffered idx4 planes, lgkm-only barriers) -> horizontal
//           box -> A,b out (fp16) + A,b chunk sums (f32).
// kfusedQ : A,b (+AB chunks) -> same -> q = meanA*I + meanb -> d_out (f32).
// N = cntH(h)*cntW(w) analytic. All dispatches measured at ~5.4 TB/s logical
// delivery -- within ~15% of the structural traffic floor.

#define HD 1024
#define WD 1024
#define ROW4 WD                      // float4 pixels per row
#define IMG4 ((size_t)HD * ROW4)
#define IMGF (IMG4 * 4)
#define BH 16                        // output rows per block == chunk height
#define NB (HD / BH)                 // 64 bands
#define CH 16
#define NCH (HD / CH)                // 64 chunks
#define TPB 256
#define PPT 4                        // pixels per thread (full width)
#define PFXN 1153                    // idx4(1024)+1
#define EPS 1e-8f

__device__ __forceinline__ int idx4(int p) { return p + (p >> 3); }

// lgkm-only barrier: prefetched global loads stay in flight across it.
__device__ __forceinline__ void barrier_lds() {
    asm volatile("s_waitcnt lgkmcnt(0)" ::: "memory");
    __builtin_amdgcn_s_barrier();
}

struct H4 { __half2 lo, hi; };

__device__ __forceinline__ H4 pack4(float4 v) {
    H4 h; h.lo = __floats2half2_rn(v.x, v.y); h.hi = __floats2half2_rn(v.z, v.w);
    return h;
}
__device__ __forceinline__ float4 unpack4(H4 h) {
    float2 l = __half22float2(h.lo), u = __half22float2(h.hi);
    return make_float4(l.x, l.y, u.x, u.y);
}
__device__ __forceinline__ float4 packAB(H4 a, H4 b) {
    union { H4 h[2]; float4 f; } u; u.h[0] = a; u.h[1] = b; return u.f;
}
__device__ __forceinline__ float4 f4add(float4 a, float4 b) {
    return make_float4(a.x + b.x, a.y + b.y, a.z + b.z, a.w + b.w);
}
__device__ __forceinline__ float4 f4sub(float4 a, float4 b) {
    return make_float4(a.x - b.x, a.y - b.y, a.z - b.z, a.w - b.w);
}
__device__ __forceinline__ float4 f4s(float4 a, float s) {
    return make_float4(a.x * s, a.y * s, a.z * s, a.w * s);
}
__device__ __forceinline__ float4 f4mul(float4 a, float4 b) {
    return make_float4(a.x * b.x, a.y * b.y, a.z * b.z, a.w * b.w);
}
__device__ __forceinline__ float4 shup4(float4 v, int d) {
    return make_float4(__shfl_up(v.x, d), __shfl_up(v.y, d), __shfl_up(v.z, d), __shfl_up(v.w, d));
}
// 64 bands: XCD q = bx&7 gets bands 8q..8q+7. Bijective.
__device__ __forceinline__ int band_of(int bx) {
    return (bx >> 3) + (bx & 7) * 8;
}

// ---------------- K0: 16-row chunk sums of {I,p,Ip,II} (f32) ----------------
__global__ __launch_bounds__(TPB, 2) void kchunk(
    const float4* __restrict__ I4, const float4* __restrict__ P4,
    float4* __restrict__ Sc)
{
    const int cb = blockIdx.x;
    const int t = threadIdx.x;
    const size_t imgb = (size_t)blockIdx.y * IMG4;
    const float4* Ib = I4 + imgb + PPT * t;
    const float4* Pb = P4 + imgb + PPT * t;
    const float4 z4 = make_float4(0.f, 0.f, 0.f, 0.f);

    float4 sI[PPT], sp[PPT], sIp[PPT], sII[PPT];
    #pragma unroll
    for (int i = 0; i < PPT; ++i) { sI[i] = z4; sp[i] = z4; sIp[i] = z4; sII[i] = z4; }

    const int j0 = cb * CH;
    for (int j = j0; j < j0 + CH; j += 4) {
        float4 a[4][PPT], c[4][PPT];
        #pragma unroll
        for (int k = 0; k < 4; ++k) {
            const float4* Ir = Ib + (size_t)(j + k) * ROW4;
            const float4* Pr = Pb + (size_t)(j + k) * ROW4;
            #pragma unroll
            for (int i = 0; i < PPT; ++i) { a[k][i] = Ir[i]; c[k][i] = Pr[i]; }
        }
        #pragma unroll
        for (int k = 0; k < 4; ++k)
            #pragma unroll
            for (int i = 0; i < PPT; ++i) {
                sI[i] = f4add(sI[i], a[k][i]);
                sp[i] = f4add(sp[i], c[k][i]);
                sIp[i] = f4add(sIp[i], f4mul(a[k][i], c[k][i]));
                sII[i] = f4add(sII[i], f4mul(a[k][i], a[k][i]));
            }
    }

    const size_t fstride = (size_t)NCH * ROW4;
    float4* S = Sc + (size_t)blockIdx.y * 4 * fstride + (size_t)cb * ROW4 + PPT * t;
    #pragma unroll
    for (int i = 0; i < PPT; ++i) {
        S[i] = sI[i];
        S[fstride + i] = sp[i];
        S[2 * fstride + i] = sIp[i];
        S[3 * fstride + i] = sII[i];
    }
}

// Block scan of 4 fields (PPT=4/thread) into swizzled planes pl[f][idx4(p)].
__device__ __forceinline__ void scan4d(
    float4 (*pl)[PFXN], float4 (*wt)[4],
    const float4* s0, const float4* s1, const float4* s2, const float4* s3,
    int t, int lane, int wv)
{
    const float4 z4 = make_float4(0.f, 0.f, 0.f, 0.f);
    float4 p0[PPT], p1[PPT], p2[PPT], p3[PPT];
    p0[0] = s0[0]; p1[0] = s1[0]; p2[0] = s2[0]; p3[0] = s3[0];
    #pragma unroll
    for (int i = 1; i < PPT; ++i) {
        p0[i] = f4add(p0[i-1], s0[i]); p1[i] = f4add(p1[i-1], s1[i]);
        p2[i] = f4add(p2[i-1], s2[i]); p3[i] = f4add(p3[i-1], s3[i]);
    }
    float4 i0 = p0[3], i1 = p1[3], i2 = p2[3], i3 = p3[3];
    #pragma unroll
    for (int d = 1; d < 64; d <<= 1) {
        float4 t0 = shup4(i0, d), t1 = shup4(i1, d), t2 = shup4(i2, d), t3 = shup4(i3, d);
        if (lane >= d) {
            i0 = f4add(i0, t0); i1 = f4add(i1, t1);
            i2 = f4add(i2, t2); i3 = f4add(i3, t3);
        }
    }
    float4 e0 = shup4(i0, 1), e1 = shup4(i1, 1), e2 = shup4(i2, 1), e3 = shup4(i3, 1);
    if (lane == 0) { e0 = z4; e1 = z4; e2 = z4; e3 = z4; }
    if (lane == 63) { wt[wv][0] = i0; wt[wv][1] = i1; wt[wv][2] = i2; wt[wv][3] = i3; }
    barrier_lds();
    for (int wq = 0; wq < wv; ++wq) {
        e0 = f4add(e0, wt[wq][0]); e1 = f4add(e1, wt[wq][1]);
        e2 = f4add(e2, wt[wq][2]); e3 = f4add(e3, wt[wq][3]);
    }
    if (t == 0) {
        pl[0][idx4(0)] = z4; pl[1][idx4(0)] = z4;
        pl[2][idx4(0)] = z4; pl[3][idx4(0)] = z4;
    }
    #pragma unroll
    for (int i = 0; i < PPT; ++i) {
        int p = PPT * t + 1 + i;
        pl[0][idx4(p)] = f4add(e0, p0[i]);
        pl[1][idx4(p)] = f4add(e1, p1[i]);
        pl[2][idx4(p)] = f4add(e2, p2[i]);
        pl[3][idx4(p)] = f4add(e3, p3[i]);
    }
    barrier_lds();
}

__device__ __forceinline__ void scan2d(
    float4 (*pl)[PFXN], float4 (*wt)[2],
    const float4* s0, const float4* s1, int t, int lane, int wv)
{
    const float4 z4 = make_float4(0.f, 0.f, 0.f, 0.f);
    float4 p0[PPT], p1[PPT];
    p0[0] = s0[0]; p1[0] = s1[0];
    #pragma unroll
    for (int i = 1; i < PPT; ++i) {
        p0[i] = f4add(p0[i-1], s0[i]); p1[i] = f4add(p1[i-1], s1[i]);
    }
    float4 i0 = p0[3], i1 = p1[3];
    #pragma unroll
    for (int d = 1; d < 64; d <<= 1) {
        float4 t0 = shup4(i0, d), t1 = shup4(i1, d);
        if (lane >= d) { i0 = f4add(i0, t0); i1 = f4add(i1, t1); }
    }
    float4 e0 = shup4(i0, 1), e1 = shup4(i1, 1);
    if (lane == 0) { e0 = z4; e1 = z4; }
    if (lane == 63) { wt[wv][0] = i0; wt[wv][1] = i1; }
    barrier_lds();
    for (int wq = 0; wq < wv; ++wq) {
        e0 = f4add(e0, wt[wq][0]); e1 = f4add(e1, wt[wq][1]);
    }
    if (t == 0) { pl[0][idx4(0)] = z4; pl[1][idx4(0)] = z4; }
    #pragma unroll
    for (int i = 0; i < PPT; ++i) {
        int p = PPT * t + 1 + i;
        pl[0][idx4(p)] = f4add(e0, p0[i]);
        pl[1][idx4(p)] = f4add(e1, p1[i]);
    }
    barrier_lds();
}

// ---------------- KA: I,p (+chunks) -> A,b (fp16) + A,b chunk sums ----------------
__global__ __launch_bounds__(TPB, 1) void kfusedAB(
    const float4* __restrict__ I4, const float4* __restrict__ P4,
    const float4* __restrict__ Sc,
    H4* __restrict__ Aout, H4* __restrict__ Bout,
    float4* __restrict__ ScAB,
    const int* __restrict__ rptr)
{
    __shared__ float4 pl[2][4][PFXN];   // double-buffered planes, 147.6 KB
    __shared__ float4 wt[2][4][4];
    const int r = *rptr;
    const int t = threadIdx.x, lane = t & 63, wv = t >> 6;
    const int band = band_of(blockIdx.x);
    const int h0 = band * BH;
    const size_t imgb = (size_t)blockIdx.y * IMG4;
    const float4* Ib = I4 + imgb + PPT * t;
    const float4* Pb = P4 + imgb + PPT * t;
    const size_t fstride = (size_t)NCH * ROW4;
    const float4* Scimg = Sc + (size_t)blockIdx.y * 4 * fstride + PPT * t;
    H4* Ao = Aout + imgb;
    H4* Bo = Bout + imgb;
    const float4 z4 = make_float4(0.f, 0.f, 0.f, 0.f);

    float4 sI[PPT], sp[PPT], sIp[PPT], sII[PPT];
    float4 cA[PPT], cB[PPT];            // A,b chunk-sum accumulators
    #pragma unroll
    for (int i = 0; i < PPT; ++i) {
        sI[i] = z4; sp[i] = z4; sIp[i] = z4; sII[i] = z4;
        cA[i] = z4; cB[i] = z4;
    }

    auto rawRows = [&](int a, int b) {
        int j = a;
        for (; j + 3 <= b; j += 4) {
            float4 aa[4][PPT], cc[4][PPT];
            #pragma unroll
            for (int k = 0; k < 4; ++k) {
                const float4* Ir = Ib + (size_t)(j + k) * ROW4;
                const float4* Pr = Pb + (size_t)(j + k) * ROW4;
                #pragma unroll
                for (int i = 0; i < PPT; ++i) { aa[k][i] = Ir[i]; cc[k][i] = Pr[i]; }
            }
            #pragma unroll
            for (int k = 0; k < 4; ++k)
                #pragma unroll
                for (int i = 0; i < PPT; ++i) {
                    sI[i] = f4add(sI[i], aa[k][i]);
                    sp[i] = f4add(sp[i], cc[k][i]);
                    sIp[i] = f4add(sIp[i], f4mul(aa[k][i], cc[k][i]));
                    sII[i] = f4add(sII[i], f4mul(aa[k][i], aa[k][i]));
                }
        }
        for (; j <= b; ++j) {
            const float4* Ir = Ib + (size_t)j * ROW4;
            const float4* Pr = Pb + (size_t)j * ROW4;
            #pragma unroll
            for (int i = 0; i < PPT; ++i) {
                float4 a1 = Ir[i], c1 = Pr[i];
                sI[i] = f4add(sI[i], a1); sp[i] = f4add(sp[i], c1);
                sIp[i] = f4add(sIp[i], f4mul(a1, c1));
                sII[i] = f4add(sII[i], f4mul(a1, a1));
            }
        }
    };

    int lo = h0 - r; if (lo < 0) lo = 0;
    int hi = h0 + r; if (hi > HD - 1) hi = HD - 1;
    int cb0 = (lo + CH - 1) / CH;
    int cb1 = (hi + 1) / CH - 1;
    if (cb0 > cb1) {
        rawRows(lo, hi);
    } else {
        if (lo < cb0 * CH) rawRows(lo, cb0 * CH - 1);
        for (int cb = cb0; cb <= cb1; ++cb) {
            const float4* S = Scimg + (size_t)cb * ROW4;
            float4 v0[PPT], v1[PPT], v2[PPT], v3[PPT];
            #pragma unroll
            for (int i = 0; i < PPT; ++i) {
                v0[i] = S[i];
                v1[i] = S[fstride + i];
                v2[i] = S[2 * fstride + i];
                v3[i] = S[3 * fstride + i];
            }
            #pragma unroll
            for (int i = 0; i < PPT; ++i) {
                sI[i] = f4add(sI[i], v0[i]);
                sp[i] = f4add(sp[i], v1[i]);
                sIp[i] = f4add(sIp[i], v2[i]);
                sII[i] = f4add(sII[i], v3[i]);
            }
        }
        if (hi >= (cb1 + 1) * CH) rawRows((cb1 + 1) * CH, hi);
    }

    for (int h = h0; h < h0 + BH; ++h) {
        const int buf = h & 1;
        int ja = h + 1 + r, js = h - r;
        float wa  = (ja <= HD - 1) ? 1.f : 0.f;
        float wsb = (js >= 0) ? 1.f : 0.f;
        int jac = (ja <= HD - 1) ? ja : HD - 1;
        int jsc = (js >= 0) ? js : 0;
        const float4* Iar = Ib + (size_t)jac * ROW4;
        const float4* Par = Pb + (size_t)jac * ROW4;
        const float4* Isr = Ib + (size_t)jsc * ROW4;
        const float4* Psr = Pb + (size_t)jsc * ROW4;
        float4 La[PPT], Ca[PPT], Ls[PPT], Cs[PPT];
        #pragma unroll
        for (int i = 0; i < PPT; ++i) {
            La[i] = Iar[i]; Ca[i] = Par[i];
            Ls[i] = Isr[i]; Cs[i] = Psr[i];
        }

        int hl = h - r; if (hl < 0) hl = 0;
        int hh = h + r; if (hh > HD - 1) hh = HD - 1;
        const float cntH = (float)(hh - hl + 1);

        scan4d(pl[buf], wt[buf], sI, sp, sIp, sII, t, lane, wv);

        H4 av[PPT], bv[PPT];
        #pragma unroll
        for (int i = 0; i < PPT; ++i) {
            int wp = PPT * t + i;
            int wl = wp - r; if (wl < 0) wl = 0;
            int wh2 = wp + r; if (wh2 > WD - 1) wh2 = WD - 1;
            float invN = 1.f / ((float)(wh2 - wl + 1) * cntH);
            int iA = idx4(wh2 + 1), iB = idx4(wl);
            float4 mI  = f4s(f4sub(pl[buf][0][iA], pl[buf][0][iB]), invN);
            float4 mp  = f4s(f4sub(pl[buf][1][iA], pl[buf][1][iB]), invN);
            float4 mIp = f4s(f4sub(pl[buf][2][iA], pl[buf][2][iB]), invN);
            float4 mII = f4s(f4sub(pl[buf][3][iA], pl[buf][3][iB]), invN);
            float4 cov = f4sub(mIp, f4mul(mI, mp));
            float4 var = f4sub(mII, f4mul(mI, mI));
            float4 Av = make_float4(cov.x / (var.x + EPS), cov.y / (var.y + EPS),
                                    cov.z / (var.z + EPS), cov.w / (var.w + EPS));
            float4 Bv = f4sub(mp, f4mul(Av, mI));
            cA[i] = f4add(cA[i], Av);
            cB[i] = f4add(cB[i], Bv);
            av[i] = pack4(Av); bv[i] = pack4(Bv);
        }
        {
            float4* Arow = (float4*)(Ao + (size_t)h * ROW4 + PPT * t);
            float4* Brow = (float4*)(Bo + (size_t)h * ROW4 + PPT * t);
            Arow[0] = packAB(av[0], av[1]); Arow[1] = packAB(av[2], av[3]);
            Brow[0] = packAB(bv[0], bv[1]); Brow[1] = packAB(bv[2], bv[3]);
        }

        #pragma unroll
        for (int i = 0; i < PPT; ++i) {
            float4 A1 = f4s(La[i], wa),  C1 = f4s(Ca[i], wa);
            float4 A2 = f4s(Ls[i], wsb), C2 = f4s(Cs[i], wsb);
            sI[i] = f4add(f4sub(sI[i], A2), A1);
            sp[i] = f4add(f4sub(sp[i], C2), C1);
            sIp[i] = f4add(sIp[i], f4sub(f4mul(A1, C1), f4mul(A2, C2)));
            sII[i] = f4add(sII[i], f4sub(f4mul(A1, A1), f4mul(A2, A2)));
        }
    }

    // store A,b chunk sums for this band (band == chunk since BH == CH)
    {
        const size_t f2 = (size_t)NCH * ROW4;
        float4* S2 = ScAB + (size_t)blockIdx.y * 2 * f2 + (size_t)band * ROW4 + PPT * t;
        #pragma unroll
        for (int i = 0; i < PPT; ++i) {
            S2[i] = cA[i];
            S2[f2 + i] = cB[i];
        }
    }
}

// ---------------- KB: A,b (+AB chunks) -> q = meanA*I + meanb ----------------
__global__ __launch_bounds__(TPB, 1) void kfusedQ(
    const H4* __restrict__ Ain, const H4* __restrict__ Bin,
    const float4* __restrict__ ScAB,
    const float4* __restrict__ I4, float4* __restrict__ Qout,
    const int* __restrict__ rptr)
{
    __shared__ float4 pl[2][2][PFXN];   // 73.8 KB
    __shared__ float4 wt[2][4][2];
    const int r = *rptr;
    const int t = threadIdx.x, lane = t & 63, wv = t >> 6;
    const int h0 = band_of(blockIdx.x) * BH;
    const size_t imgb = (size_t)blockIdx.y * IMG4;
    const H4* Abp = Ain + imgb + PPT * t;
    const H4* Bbp = Bin + imgb + PPT * t;
    const size_t f2 = (size_t)NCH * ROW4;
    const float4* S2img = ScAB + (size_t)blockIdx.y * 2 * f2 + PPT * t;
    const float4* Ib = I4 + imgb + PPT * t;
    float4* Qo = Qout + imgb;
    const float4 z4 = make_float4(0.f, 0.f, 0.f, 0.f);

    float4 sA[PPT], sB[PPT];
    #pragma unroll
    for (int i = 0; i < PPT; ++i) { sA[i] = z4; sB[i] = z4; }

    auto rawRows = [&](int a, int b) {
        int j = a;
        for (; j + 3 <= b; j += 4) {
            H4 aa[4][PPT], bb[4][PPT];
            #pragma unroll
            for (int k = 0; k < 4; ++k) {
                const H4* Ar = Abp + (size_t)(j + k) * ROW4;
                const H4* Br = Bbp + (size_t)(j + k) * ROW4;
                #pragma unroll
                for (int i = 0; i < PPT; ++i) { aa[k][i] = Ar[i]; bb[k][i] = Br[i]; }
            }
            #pragma unroll
            for (int k = 0; k < 4; ++k)
                #pragma unroll
                for (int i = 0; i < PPT; ++i) {
                    sA[i] = f4add(sA[i], unpack4(aa[k][i]));
                    sB[i] = f4add(sB[i], unpack4(bb[k][i]));
                }
        }
        for (; j <= b; ++j) {
            const H4* Ar = Abp + (size_t)j * ROW4;
            const H4* Br = Bbp + (size_t)j * ROW4;
            #pragma unroll
            for (int i = 0; i < PPT; ++i) {
                sA[i] = f4add(sA[i], unpack4(Ar[i]));
                sB[i] = f4add(sB[i], unpack4(Br[i]));
            }
        }
    };

    int lo = h0 - r; if (lo < 0) lo = 0;
    int hi = h0 + r; if (hi > HD - 1) hi = HD - 1;
    int cb0 = (lo + CH - 1) / CH;
    int cb1 = (hi + 1) / CH - 1;
    if (cb0 > cb1) {
        rawRows(lo, hi);
    } else {
        if (lo < cb0 * CH) rawRows(lo, cb0 * CH - 1);
        for (int cb = cb0; cb <= cb1; ++cb) {
            const float4* S = S2img + (size_t)cb * ROW4;
            float4 v0[PPT], v1[PPT];
            #pragma unroll
            for (int i = 0; i < PPT; ++i) {
                v0[i] = S[i];
                v1[i] = S[f2 + i];
            }
            #pragma unroll
            for (int i = 0; i < PPT; ++i) {
                sA[i] = f4add(sA[i], v0[i]);
                sB[i] = f4add(sB[i], v1[i]);
            }
        }
        if (hi >= (cb1 + 1) * CH) rawRows((cb1 + 1) * CH, hi);
    }

    for (int h = h0; h < h0 + BH; ++h) {
        const int buf = h & 1;
        int ja = h + 1 + r, js = h - r;
        float wa  = (ja <= HD - 1) ? 1.f : 0.f;
        float wsb = (js >= 0) ? 1.f : 0.f;
        int jac = (ja <= HD - 1) ? ja : HD - 1;
        int jsc = (js >= 0) ? js : 0;
        const H4* Aar = Abp + (size_t)jac * ROW4;
        const H4* Bar = Bbp + (size_t)jac * ROW4;
        const H4* Asr = Abp + (size_t)jsc * ROW4;
        const H4* Bsr = Bbp + (size_t)jsc * ROW4;
        const float4* Irow = Ib + (size_t)h * ROW4;
        H4 La[PPT], Lb[PPT], Sa[PPT], Sb[PPT];
        float4 iv[PPT];
        #pragma unroll
        for (int i = 0; i < PPT; ++i) {
            La[i] = Aar[i]; Lb[i] = Bar[i];
            Sa[i] = Asr[i]; Sb[i] = Bsr[i];
            iv[i] = Irow[i];
        }

        int hl = h - r; if (hl < 0) hl = 0;
        int hh = h + r; if (hh > HD - 1) hh = HD - 1;
        const float cntH = (float)(hh - hl + 1);

        scan2d(pl[buf], wt[buf], sA, sB, t, lane, wv);

        float4* Qrow = Qo + (size_t)h * ROW4 + PPT * t;
        #pragma unroll
        for (int i = 0; i < PPT; ++i) {
            int wp = PPT * t + i;
            int wl = wp - r; if (wl < 0) wl = 0;
            int wh2 = wp + r; if (wh2 > WD - 1) wh2 = WD - 1;
            float invN = 1.f / ((float)(wh2 - wl + 1) * cntH);
            int iA = idx4(wh2 + 1), iB = idx4(wl);
            float4 mA = f4s(f4sub(pl[buf][0][iA], pl[buf][0][iB]), invN);
            float4 mB = f4s(f4sub(pl[buf][1][iA], pl[buf][1][iB]), invN);
            Qrow[i] = make_float4(mA.x * iv[i].x + mB.x, mA.y * iv[i].y + mB.y,
                                  mA.z * iv[i].z + mB.z, mA.w * iv[i].w + mB.w);
        }

        #pragma unroll
        for (int i = 0; i < PPT; ++i) {
            float4 A1 = f4s(unpack4(La[i]), wa);
            float4 B1 = f4s(unpack4(Lb[i]), wa);
            float4 A2 = f4s(unpack4(Sa[i]), wsb);
            float4 B2 = f4s(unpack4(Sb[i]), wsb);
            sA[i] = f4add(f4sub(sA[i], A2), A1);
            sB[i] = f4add(f4sub(sB[i], B2), B1);
        }
    }
}

extern "C" void kernel_launch(void* const* d_in, const int* in_sizes, int n_in,
                              void* d_out, int out_size, void* d_ws, size_t ws_size,
                              hipStream_t stream)
{
    const float* I = (const float*)d_in[0];
    const float* P = (const float*)d_in[1];
    const int* rptr = (const int*)d_in[2];
    float* out = (float*)d_out;

    const int Bn = (int)(in_sizes[0] / IMGF);              // 4
    const size_t chunkBytes  = (size_t)4 * NCH * ROW4 * sizeof(float4);  // 4 MiB/img
    const size_t chunkABytes = (size_t)2 * NCH * ROW4 * sizeof(float4);  // 2 MiB/img
    const size_t perBatch = 2 * IMG4 * sizeof(H4) + chunkBytes + chunkABytes;

    int nbChunk = (int)(ws_size / perBatch);
    if (nbChunk < 1) nbChunk = 1;
    if (nbChunk > Bn) nbChunk = Bn;

    for (int b0 = 0; b0 < Bn; b0 += nbChunk) {
        const int nb = (b0 + nbChunk <= Bn) ? nbChunk : (Bn - b0);
        H4* Ah = (H4*)d_ws;
        H4* Bh = Ah + (size_t)nb * IMG4;
        float4* Sc = (float4*)(Bh + (size_t)nb * IMG4);
        float4* ScAB = Sc + (size_t)nb * 4 * NCH * ROW4;
        const float4* Ib = (const float4*)(I + (size_t)b0 * IMGF);
        const float4* Pb = (const float4*)(P + (size_t)b0 * IMGF);
        float4* ob = (float4*)(out + (size_t)b0 * IMGF);

        kchunk<<<dim3(NCH, nb), TPB, 0, stream>>>(Ib, Pb, Sc);
        kfusedAB<<<dim3(NB, nb), TPB, 0, stream>>>(Ib, Pb, Sc, Ah, Bh, ScAB, rptr);
        kfusedQ<<<dim3(NB, nb), TPB, 0, stream>>>(Ah, Bh, ScAB, Ib, ob, rptr);
    }
}